// Round 1
// baseline (628.300 us; speedup 1.0000x reference)
//
#include <hip/hip_runtime.h>
#include <hip/hip_bf16.h>
#include <stdint.h>
#include <math.h>

// B=4, N=1024, D=1024, H=8, DK=128, L=512. All internal tensors bf16 in ws.
// GEMM convention everywhere: C[m,n] = sum_k A[m,k]*B[n,k]  (B stored [N,K]).

typedef __attribute__((ext_vector_type(8))) __bf16 bf16x8;
typedef __attribute__((ext_vector_type(4))) float f32x4;

#define DEV static __device__ __forceinline__

DEV float bf2f(unsigned short u){ union { unsigned int i; float f; } x; x.i = ((unsigned int)u) << 16; return x.f; }
DEV unsigned short f2bf(float f){ union { float f; unsigned int i; } x; x.f = f;
  unsigned int r = x.i + 0x7FFFu + ((x.i >> 16) & 1u); return (unsigned short)(r >> 16); }

#define GLDS16(gp, lp) __builtin_amdgcn_global_load_lds( \
    (const __attribute__((address_space(1))) void*)(gp), \
    (__attribute__((address_space(3))) void*)(lp), 16, 0, 0)

// ---------------- f32 -> bf16 convert (float4 vectorized) ----------------
__global__ __launch_bounds__(256) void k_convert(const float* __restrict__ src,
                                                 unsigned short* __restrict__ dst, int n4){
  for (int i = blockIdx.x * blockDim.x + threadIdx.x; i < n4; i += gridDim.x * blockDim.x){
    float4 v = ((const float4*)src)[i];
    ushort4 o; o.x = f2bf(v.x); o.y = f2bf(v.y); o.z = f2bf(v.z); o.w = f2bf(v.w);
    ((ushort4*)dst)[i] = o;
  }
}

// ---------------- W [K,N] f32 -> WT [N,K] bf16 (LDS tile transpose) ----------------
__global__ __launch_bounds__(256) void k_wtrans(const float* __restrict__ W,
                                                unsigned short* __restrict__ WT, int K, int N){
  __shared__ unsigned short t[64][65];
  int n0 = blockIdx.x * 64, k0 = blockIdx.y * 64;
  int tx = threadIdx.x, ty = threadIdx.y;
  for (int r = ty; r < 64; r += 4) t[r][tx] = f2bf(W[(long)(k0 + r) * N + n0 + tx]);
  __syncthreads();
  for (int r = ty; r < 64; r += 4) WT[(long)(n0 + r) * K + k0 + tx] = t[tx][r];
}

// ---------------- v [z][1024][128] -> vT [z][128][1024] (bf16) ----------------
__global__ __launch_bounds__(256) void k_vtrans(const unsigned short* __restrict__ V,
                                                unsigned short* __restrict__ VT){
  __shared__ unsigned short t[64][65];
  int z = blockIdx.z, d0 = blockIdx.x * 64, j0 = blockIdx.y * 64;
  int tx = threadIdx.x, ty = threadIdx.y;
  const unsigned short* v = V + (long)z * 131072;
  unsigned short* vt = VT + (long)z * 131072;
  for (int r = ty; r < 64; r += 4) t[r][tx] = v[(j0 + r) * 128 + d0 + tx];
  __syncthreads();
  for (int r = ty; r < 64; r += 4) vt[(d0 + r) * 1024 + j0 + tx] = t[tx][r];
}

// ---------------- GEMM: 128x128 tile, BK=32, 4 waves (2x2), m97 structure ----------------
// MODE 0: plain bf16 out [z][M][N]                       (p2c/c2p tables)
// MODE 1: bf16 out, (acc+bias)*scale, head-split remap   (projections)
// MODE 2: f32 out [M][N], +bias                          (final projection)
// MODE 3: score epilogue: + gather(Pt, rel^T) + gather(Cc, rel), mask -> -1e9, bf16 [z][1024][1024]
// MODE 4: bf16 out, PV remap -> out_heads[b][i][h*128+dk]
template<int MODE>
__global__ __launch_bounds__(256) void k_gemm(
    const unsigned short* __restrict__ A, long sAz,
    const unsigned short* __restrict__ B, long sBz, int bzMask,
    void* __restrict__ Cout, const float* __restrict__ bias, float scale,
    int M, int N, int K, int logSeq, int headBase,
    const int* __restrict__ rel, const int* __restrict__ maskp,
    const unsigned short* __restrict__ Pt, const unsigned short* __restrict__ Cc)
{
  __shared__ unsigned short Al[128 * 32];
  __shared__ unsigned short Bl[128 * 32];
  const int tid = threadIdx.x;
  const int lane = tid & 63, wave = tid >> 6;
  const int z = blockIdx.z;
  const unsigned short* Az = A + (long)z * sAz;
  const unsigned short* Bz = B + (long)(z & bzMask) * sBz;
  const int m0 = blockIdx.y * 128, n0 = blockIdx.x * 128;
  const int lr = lane & 15, lk = lane >> 4;
  const int wr = wave >> 1, wc = wave & 1;

  f32x4 acc[4][4] = {};

  // staging: thread t loads 16B of row (t>>2), quarter (t&3); LDS is linear row-major [row][32]
  const unsigned short* ga = Az + (long)(m0 + (tid >> 2)) * K + (tid & 3) * 8;
  const unsigned short* gb = Bz + (long)(n0 + (tid >> 2)) * K + (tid & 3) * 8;
  unsigned short* lA = Al + wave * 512;   // wave-uniform LDS base (HW adds lane*16B)
  unsigned short* lB = Bl + wave * 512;
  const long rowStep = (long)64 * K;

  for (int kt = 0; kt < K; kt += 32){
    GLDS16(ga + kt,           lA);
    GLDS16(ga + kt + rowStep, lA + 64 * 32);
    GLDS16(gb + kt,           lB);
    GLDS16(gb + kt + rowStep, lB + 64 * 32);
    __syncthreads();
    bf16x8 af[4], bfr[4];
    #pragma unroll
    for (int mi = 0; mi < 4; mi++) af[mi]  = *(const bf16x8*)&Al[(wr * 64 + mi * 16 + lr) * 32 + lk * 8];
    #pragma unroll
    for (int ni = 0; ni < 4; ni++) bfr[ni] = *(const bf16x8*)&Bl[(wc * 64 + ni * 16 + lr) * 32 + lk * 8];
    #pragma unroll
    for (int mi = 0; mi < 4; mi++)
      #pragma unroll
      for (int ni = 0; ni < 4; ni++)
        acc[mi][ni] = __builtin_amdgcn_mfma_f32_16x16x32_bf16(af[mi], bfr[ni], acc[mi][ni], 0, 0, 0);
    __syncthreads();
  }

  const int seqMask = (1 << logSeq) - 1;
  #pragma unroll
  for (int mi = 0; mi < 4; mi++){
    #pragma unroll
    for (int ni = 0; ni < 4; ni++){
      #pragma unroll
      for (int r = 0; r < 4; r++){
        const int row = m0 + wr * 64 + mi * 16 + (lane >> 4) * 4 + r;  // verified C layout
        const int col = n0 + wc * 64 + ni * 16 + (lane & 15);
        float v = acc[mi][ni][r];
        if constexpr (MODE == 0){
          ((unsigned short*)Cout)[(long)z * M * N + (long)row * N + col] = f2bf(v);
        } else if constexpr (MODE == 1){
          v = (v + bias[col]) * scale;
          long idx = (((long)(row >> logSeq) * 8 + headBase + (col >> 7)) * (long)(seqMask + 1)
                      + (row & seqMask)) * 128 + (col & 127);
          ((unsigned short*)Cout)[idx] = f2bf(v);
        } else if constexpr (MODE == 2){
          ((float*)Cout)[(long)row * N + col] = v + bias[col];
        } else if constexpr (MODE == 3){
          const int* relz = rel + (long)z * 1048576;
          int rij = relz[row * 1024 + col];   // rel[b,h,i,j] -> c2p gather
          int rji = relz[col * 1024 + row];   // rel[b,h,j,i] -> p2c gather
          v += bf2f(Pt[((long)z * 1024 + col) * 512 + rji])
             + bf2f(Cc[((long)z * 1024 + row) * 512 + rij]);
          if (maskp[((long)(z >> 3) * 1024 + row) * 1024 + col] == 1) v = -1e9f;
          ((unsigned short*)Cout)[(long)z * 1048576 + (long)row * 1024 + col] = f2bf(v);
        } else { // MODE 4: out_heads[b][i][h*128+dk]
          ((unsigned short*)Cout)[((long)(z >> 3) * 1024 + row) * 1024 + (z & 7) * 128 + col] = f2bf(v);
        }
      }
    }
  }
}

// ---------------- row softmax, in-place, 1 wave per row of 1024 ----------------
__global__ __launch_bounds__(256) void k_softmax(unsigned short* __restrict__ S){
  const long row = (long)blockIdx.x * 4 + (threadIdx.x >> 6);
  const int lane = threadIdx.x & 63;
  unsigned short* p = S + row * 1024 + lane * 16;
  uint4 w0 = *(const uint4*)p;
  uint4 w1 = *(const uint4*)(p + 8);
  unsigned int wa[8] = {w0.x, w0.y, w0.z, w0.w, w1.x, w1.y, w1.z, w1.w};
  float f[16];
  #pragma unroll
  for (int i = 0; i < 8; i++){
    f[2*i]   = bf2f((unsigned short)(wa[i] & 0xFFFFu));
    f[2*i+1] = bf2f((unsigned short)(wa[i] >> 16));
  }
  float m = f[0];
  #pragma unroll
  for (int i = 1; i < 16; i++) m = fmaxf(m, f[i]);
  #pragma unroll
  for (int o = 32; o; o >>= 1) m = fmaxf(m, __shfl_xor(m, o));
  float s = 0.f;
  #pragma unroll
  for (int i = 0; i < 16; i++){ f[i] = __expf(f[i] - m); s += f[i]; }
  #pragma unroll
  for (int o = 32; o; o >>= 1) s += __shfl_xor(s, o);
  float inv = 1.0f / s;
  unsigned int ob[8];
  #pragma unroll
  for (int i = 0; i < 8; i++)
    ob[i] = (unsigned)f2bf(f[2*i] * inv) | ((unsigned)f2bf(f[2*i+1] * inv) << 16);
  *(uint4*)p       = make_uint4(ob[0], ob[1], ob[2], ob[3]);
  *(uint4*)(p + 8) = make_uint4(ob[4], ob[5], ob[6], ob[7]);
}

extern "C" void kernel_launch(void* const* d_in, const int* in_sizes, int n_in,
                              void* d_out, int out_size, void* d_ws, size_t ws_size,
                              hipStream_t stream){
  (void)in_sizes; (void)n_in; (void)out_size; (void)ws_size;
  const float* query = (const float*)d_in[0];
  const float* key_  = (const float*)d_in[1];
  const float* value = (const float*)d_in[2];
  const float* rele  = (const float*)d_in[3];
  const int*   rel   = (const int*)d_in[4];
  const int*   mask  = (const int*)d_in[5];
  const float* Wq = (const float*)d_in[6];  const float* bq = (const float*)d_in[7];
  const float* Wk = (const float*)d_in[8];  const float* bk = (const float*)d_in[9];
  const float* Wv = (const float*)d_in[10]; const float* bv = (const float*)d_in[11];
  const float* Wo = (const float*)d_in[12]; const float* bo = (const float*)d_in[13];
  const float* Wlq = (const float*)d_in[14]; const float* blq = (const float*)d_in[15];
  const float* Wlk = (const float*)d_in[16]; const float* blk = (const float*)d_in[17];
  const float* Wtq = (const float*)d_in[18]; const float* btq = (const float*)d_in[19];
  const float* Wtk = (const float*)d_in[20]; const float* btk = (const float*)d_in[21];

  char* ws = (char*)d_ws;
  auto U = [&](size_t off){ return (unsigned short*)(ws + off); };
  // region 0..64MB: score S; convert staging (dead before score) aliases into it
  unsigned short* S    = U(0);
  unsigned short* qf   = U(0);
  unsigned short* kf   = U(8388608);
  unsigned short* vf   = U(16777216);
  unsigned short* lt   = U(25165824);       // rel_emb bf16: l then t
  unsigned short* WqT  = U(27262976);
  unsigned short* WkT  = U(29360128);
  unsigned short* WvT  = U(31457280);
  unsigned short* WlqT = U(33554432);
  unsigned short* WlkT = U(34603008);
  unsigned short* WtqT = U(35651584);
  unsigned short* WtkT = U(36700160);
  unsigned short* WoT  = U(67108864);
  unsigned short* qs   = U(69206016);       // scaled q  [B,H,N,DK]
  unsigned short* kk   = U(77594624);       // k         [B,H,N,DK]
  unsigned short* vv   = U(85983232);       // v         [B,H,N,DK]
  unsigned short* oh   = U(85983232);       // out_heads aliases vv (vv dead after vtrans)
  unsigned short* vT   = U(94371840);       // v^T       [B,H,DK,N]
  unsigned short* lqs  = U(102760448);      // scaled lq [H,L,DK]
  unsigned short* lks  = U(103809024);      // lk        [H,L,DK]
  unsigned short* Pt   = U(104857600);      // p2c^T     [B,H,N(j),L(r)]
  unsigned short* Cc   = U(138412032);      // c2p       [B,H,N(i),L(l)]

  const float invs = 1.0f / sqrtf(384.0f);  // 1/sqrt(3*DK)
  dim3 b256(256), b644(64, 4);

  k_convert<<<2048, b256, 0, stream>>>(query, qf, 1048576);
  k_convert<<<2048, b256, 0, stream>>>(key_,  kf, 1048576);
  k_convert<<<2048, b256, 0, stream>>>(value, vf, 1048576);
  k_convert<<<1024, b256, 0, stream>>>(rele,  lt, 262144);

  k_wtrans<<<dim3(16,16), b644, 0, stream>>>(Wq,  WqT,  1024, 1024);
  k_wtrans<<<dim3(16,16), b644, 0, stream>>>(Wk,  WkT,  1024, 1024);
  k_wtrans<<<dim3(16,16), b644, 0, stream>>>(Wv,  WvT,  1024, 1024);
  k_wtrans<<<dim3(16,16), b644, 0, stream>>>(Wo,  WoT,  1024, 1024);
  k_wtrans<<<dim3(8,16),  b644, 0, stream>>>(Wlq, WlqT, 1024, 512);
  k_wtrans<<<dim3(8,16),  b644, 0, stream>>>(Wlk, WlkT, 1024, 512);
  k_wtrans<<<dim3(8,16),  b644, 0, stream>>>(Wtq, WtqT, 1024, 512);
  k_wtrans<<<dim3(8,16),  b644, 0, stream>>>(Wtk, WtkT, 1024, 512);

  // projections (scale folded into q; covers /sqrt(384) of c2c and c2p)
  k_gemm<1><<<dim3(8,32,1), b256, 0, stream>>>(qf,0, WqT,0,0, qs, bq, invs, 4096,1024,1024, 10,0, nullptr,nullptr,nullptr,nullptr);
  k_gemm<1><<<dim3(8,32,1), b256, 0, stream>>>(kf,0, WkT,0,0, kk, bk, 1.0f, 4096,1024,1024, 10,0, nullptr,nullptr,nullptr,nullptr);
  k_gemm<1><<<dim3(8,32,1), b256, 0, stream>>>(vf,0, WvT,0,0, vv, bv, 1.0f, 4096,1024,1024, 10,0, nullptr,nullptr,nullptr,nullptr);
  // rel projections (scale folded into lq; covers /sqrt(384) of p2c)
  k_gemm<1><<<dim3(4,4,1), b256, 0, stream>>>(lt,0,        WlqT,0,0, lqs, blq, invs, 512,512,1024, 9,0, nullptr,nullptr,nullptr,nullptr);
  k_gemm<1><<<dim3(4,4,1), b256, 0, stream>>>(lt+524288,0, WtqT,0,0, lqs, btq, invs, 512,512,1024, 9,4, nullptr,nullptr,nullptr,nullptr);
  k_gemm<1><<<dim3(4,4,1), b256, 0, stream>>>(lt,0,        WlkT,0,0, lks, blk, 1.0f, 512,512,1024, 9,0, nullptr,nullptr,nullptr,nullptr);
  k_gemm<1><<<dim3(4,4,1), b256, 0, stream>>>(lt+524288,0, WtkT,0,0, lks, btk, 1.0f, 512,512,1024, 9,4, nullptr,nullptr,nullptr,nullptr);

  k_vtrans<<<dim3(2,16,32), b644, 0, stream>>>(vv, vT);

  // tables: Pt[z][j][r] = k_j . lq_r ; Cc[z][i][l] = q_i . lk_l
  k_gemm<0><<<dim3(4,8,32), b256, 0, stream>>>(kk,131072, lqs,65536,7, Pt, nullptr,1.0f, 1024,512,128, 0,0, nullptr,nullptr,nullptr,nullptr);
  k_gemm<0><<<dim3(4,8,32), b256, 0, stream>>>(qs,131072, lks,65536,7, Cc, nullptr,1.0f, 1024,512,128, 0,0, nullptr,nullptr,nullptr,nullptr);

  // score = c2c + gathers + mask
  k_gemm<3><<<dim3(8,8,32), b256, 0, stream>>>(qs,131072, kk,131072,-1, S, nullptr,1.0f, 1024,1024,128, 0,0, rel, mask, Pt, Cc);

  k_softmax<<<8192, b256, 0, stream>>>(S);

  // out_heads = att @ v
  k_gemm<4><<<dim3(1,8,32), b256, 0, stream>>>(S,1048576, vT,131072,-1, oh, nullptr,1.0f, 1024,128,1024, 0,0, nullptr,nullptr,nullptr,nullptr);

  // final: d_out = out_heads @ Wo + bo   (f32 out)
  k_gemm<2><<<dim3(8,32,1), b256, 0, stream>>>(oh,0, WoT,0,0, d_out, bo, 1.0f, 4096,1024,1024, 0,0, nullptr,nullptr,nullptr,nullptr);
}

// Round 2
// 611.381 us; speedup vs baseline: 1.0277x; 1.0277x over previous
//
#include <hip/hip_runtime.h>
#include <hip/hip_bf16.h>
#include <stdint.h>
#include <math.h>

// B=4, N=1024, D=1024, H=8, DK=128, L=512. All internal tensors bf16 in ws.
// GEMM convention everywhere: C[m,n] = sum_k A[m,k]*B[n,k]  (B stored [N,K]).

typedef __attribute__((ext_vector_type(8))) __bf16 bf16x8;
typedef __attribute__((ext_vector_type(4))) float f32x4;

#define DEV static __device__ __forceinline__

DEV float bf2f(unsigned short u){ union { unsigned int i; float f; } x; x.i = ((unsigned int)u) << 16; return x.f; }
DEV unsigned short f2bf(float f){ union { float f; unsigned int i; } x; x.f = f;
  unsigned int r = x.i + 0x7FFFu + ((x.i >> 16) & 1u); return (unsigned short)(r >> 16); }

#define GLDS16(gp, lp) __builtin_amdgcn_global_load_lds( \
    (const __attribute__((address_space(1))) void*)(gp), \
    (__attribute__((address_space(3))) void*)(lp), 16, 0, 0)

// ---------------- f32 -> bf16 convert (float4 vectorized) ----------------
__global__ __launch_bounds__(256) void k_convert(const float* __restrict__ src,
                                                 unsigned short* __restrict__ dst, int n4){
  for (int i = blockIdx.x * blockDim.x + threadIdx.x; i < n4; i += gridDim.x * blockDim.x){
    float4 v = ((const float4*)src)[i];
    ushort4 o; o.x = f2bf(v.x); o.y = f2bf(v.y); o.z = f2bf(v.z); o.w = f2bf(v.w);
    ((ushort4*)dst)[i] = o;
  }
}

// ---------------- W [K,N] f32 -> WT [N,K] bf16 (LDS tile transpose) ----------------
__global__ __launch_bounds__(256) void k_wtrans(const float* __restrict__ W,
                                                unsigned short* __restrict__ WT, int K, int N){
  __shared__ unsigned short t[64][65];
  int n0 = blockIdx.x * 64, k0 = blockIdx.y * 64;
  int tx = threadIdx.x, ty = threadIdx.y;
  for (int r = ty; r < 64; r += 4) t[r][tx] = f2bf(W[(long)(k0 + r) * N + n0 + tx]);
  __syncthreads();
  for (int r = ty; r < 64; r += 4) WT[(long)(n0 + r) * K + k0 + tx] = t[tx][r];
}

// ---------------- v [z][1024][128] -> vT [z][128][1024] (bf16) ----------------
__global__ __launch_bounds__(256) void k_vtrans(const unsigned short* __restrict__ V,
                                                unsigned short* __restrict__ VT){
  __shared__ unsigned short t[64][65];
  int z = blockIdx.z, d0 = blockIdx.x * 64, j0 = blockIdx.y * 64;
  int tx = threadIdx.x, ty = threadIdx.y;
  const unsigned short* v = V + (long)z * 131072;
  unsigned short* vt = VT + (long)z * 131072;
  for (int r = ty; r < 64; r += 4) t[r][tx] = v[(j0 + r) * 128 + d0 + tx];
  __syncthreads();
  for (int r = ty; r < 64; r += 4) vt[(d0 + r) * 1024 + j0 + tx] = t[tx][r];
}

// ---------------- GEMM: 128x128 tile, BK=32, 4 waves (2x2), m97 structure ----------------
// MODE 0: plain bf16 out [z][M][N]                       (tables, score c2c)
// MODE 1: bf16 out, (acc+bias)*scale, head-split remap   (projections)
// MODE 2: f32 out [M][N], +bias                          (final projection)
// MODE 4: bf16 out, PV remap -> out_heads[b][i][h*128+dk]
template<int MODE>
__global__ __launch_bounds__(256) void k_gemm(
    const unsigned short* __restrict__ A, long sAz,
    const unsigned short* __restrict__ B, long sBz, int bzMask,
    void* __restrict__ Cout, const float* __restrict__ bias, float scale,
    int M, int N, int K, int logSeq, int headBase)
{
  __shared__ unsigned short Al[128 * 32];
  __shared__ unsigned short Bl[128 * 32];
  const int tid = threadIdx.x;
  const int lane = tid & 63, wave = tid >> 6;
  const int z = blockIdx.z;
  const unsigned short* Az = A + (long)z * sAz;
  const unsigned short* Bz = B + (long)(z & bzMask) * sBz;
  const int m0 = blockIdx.y * 128, n0 = blockIdx.x * 128;
  const int lr = lane & 15, lk = lane >> 4;
  const int wr = wave >> 1, wc = wave & 1;

  f32x4 acc[4][4] = {};

  // staging: thread t loads 16B of row (t>>2), quarter (t&3); LDS is linear row-major [row][32]
  const unsigned short* ga = Az + (long)(m0 + (tid >> 2)) * K + (tid & 3) * 8;
  const unsigned short* gb = Bz + (long)(n0 + (tid >> 2)) * K + (tid & 3) * 8;
  unsigned short* lA = Al + wave * 512;   // wave-uniform LDS base (HW adds lane*16B)
  unsigned short* lB = Bl + wave * 512;
  const long rowStep = (long)64 * K;

  for (int kt = 0; kt < K; kt += 32){
    GLDS16(ga + kt,           lA);
    GLDS16(ga + kt + rowStep, lA + 64 * 32);
    GLDS16(gb + kt,           lB);
    GLDS16(gb + kt + rowStep, lB + 64 * 32);
    __syncthreads();
    bf16x8 af[4], bfr[4];
    #pragma unroll
    for (int mi = 0; mi < 4; mi++) af[mi]  = *(const bf16x8*)&Al[(wr * 64 + mi * 16 + lr) * 32 + lk * 8];
    #pragma unroll
    for (int ni = 0; ni < 4; ni++) bfr[ni] = *(const bf16x8*)&Bl[(wc * 64 + ni * 16 + lr) * 32 + lk * 8];
    #pragma unroll
    for (int mi = 0; mi < 4; mi++)
      #pragma unroll
      for (int ni = 0; ni < 4; ni++)
        acc[mi][ni] = __builtin_amdgcn_mfma_f32_16x16x32_bf16(af[mi], bfr[ni], acc[mi][ni], 0, 0, 0);
    __syncthreads();
  }

  const int seqMask = (1 << logSeq) - 1;
  #pragma unroll
  for (int mi = 0; mi < 4; mi++){
    #pragma unroll
    for (int ni = 0; ni < 4; ni++){
      #pragma unroll
      for (int r = 0; r < 4; r++){
        const int row = m0 + wr * 64 + mi * 16 + (lane >> 4) * 4 + r;  // verified C layout
        const int col = n0 + wc * 64 + ni * 16 + (lane & 15);
        float v = acc[mi][ni][r];
        if constexpr (MODE == 0){
          ((unsigned short*)Cout)[(long)z * M * N + (long)row * N + col] = f2bf(v);
        } else if constexpr (MODE == 1){
          v = (v + bias[col]) * scale;
          long idx = (((long)(row >> logSeq) * 8 + headBase + (col >> 7)) * (long)(seqMask + 1)
                      + (row & seqMask)) * 128 + (col & 127);
          ((unsigned short*)Cout)[idx] = f2bf(v);
        } else if constexpr (MODE == 2){
          ((float*)Cout)[(long)row * N + col] = v + bias[col];
        } else { // MODE 4: out_heads[b][i][h*128+dk]
          ((unsigned short*)Cout)[((long)(z >> 3) * 1024 + row) * 1024 + (z & 7) * 128 + col] = f2bf(v);
        }
      }
    }
  }
}

// ---------------- p2c: S[z][i][j] += Pt[z][j][ rel[z][j][i] ]  (in-place RMW) ----------------
// Block = (z, 32 j-rows). Pt rows staged in LDS once; rel reads lane-contiguous in i;
// each thread owns a 16B strip of S (the block's 4 waves jointly cover full 64B lines).
__global__ __launch_bounds__(256) void k_p2ct(unsigned short* __restrict__ S,
    const unsigned short* __restrict__ Pt, const int* __restrict__ rel){
  __shared__ unsigned short Ptl[32][512];
  const int tid = threadIdx.x, l = tid & 63, w = tid >> 6;
  const int z = blockIdx.y, j0 = blockIdx.x * 32;
  const long zb = (long)z << 20;
  {
    const char* g = (const char*)Pt + ((long)z * 1024 + j0) * 1024;  // 32 rows x 1KB
    char* lb = (char*)&Ptl[0][0];
    #pragma unroll
    for (int it = 0; it < 8; it++)
      GLDS16(g + it * 4096 + w * 1024 + l * 16, lb + it * 4096 + w * 1024);
  }
  __syncthreads();
  const int jbase = w * 8;
  for (int i0 = 0; i0 < 1024; i0 += 64){
    unsigned short* sp = S + zb + (long)(i0 + l) * 1024 + j0 + jbase;
    uint4 a = *(const uint4*)sp;
    unsigned int aw[4] = {a.x, a.y, a.z, a.w};
    float f[8];
    #pragma unroll
    for (int e = 0; e < 4; e++){
      f[2*e]   = bf2f((unsigned short)(aw[e] & 0xFFFFu));
      f[2*e+1] = bf2f((unsigned short)(aw[e] >> 16));
    }
    #pragma unroll
    for (int jj = 0; jj < 8; jj++){
      int rv = rel[zb + (long)(j0 + jbase + jj) * 1024 + i0 + l];
      f[jj] += bf2f(Ptl[jbase + jj][rv & 511]);
    }
    #pragma unroll
    for (int e = 0; e < 4; e++)
      aw[e] = (unsigned)f2bf(f[2*e]) | ((unsigned)f2bf(f[2*e+1]) << 16);
    *(uint4*)sp = make_uint4(aw[0], aw[1], aw[2], aw[3]);
  }
}

// ---------------- softmax fused with c2p gather + mask, in-place, 1 wave/row ----------------
__global__ __launch_bounds__(256) void k_softmax(unsigned short* __restrict__ S,
    const unsigned short* __restrict__ Cc, const int* __restrict__ rel,
    const int* __restrict__ maskp){
  __shared__ unsigned short crow[4][512];
  const int w = threadIdx.x >> 6, lane = threadIdx.x & 63;
  const long row = (long)blockIdx.x * 4 + w;
  const int z = (int)(row >> 10), i = (int)(row & 1023);
  *(uint4*)&crow[w][lane * 8] = *(const uint4*)&Cc[row * 512 + lane * 8];
  __syncthreads();
  unsigned short* p = S + row * 1024 + lane * 16;
  const int* rp = rel + row * 1024 + lane * 16;
  const int* mp = maskp + ((((long)(z >> 3)) << 10) + i) * 1024 + lane * 16;
  uint4 w0 = *(const uint4*)p;
  uint4 w1 = *(const uint4*)(p + 8);
  unsigned int wa[8] = {w0.x, w0.y, w0.z, w0.w, w1.x, w1.y, w1.z, w1.w};
  float f[16];
  #pragma unroll
  for (int t = 0; t < 8; t++){
    f[2*t]   = bf2f((unsigned short)(wa[t] & 0xFFFFu));
    f[2*t+1] = bf2f((unsigned short)(wa[t] >> 16));
  }
  #pragma unroll
  for (int t = 0; t < 4; t++){
    int4 rr = ((const int4*)rp)[t];
    f[4*t]   += bf2f(crow[w][rr.x & 511]);
    f[4*t+1] += bf2f(crow[w][rr.y & 511]);
    f[4*t+2] += bf2f(crow[w][rr.z & 511]);
    f[4*t+3] += bf2f(crow[w][rr.w & 511]);
  }
  #pragma unroll
  for (int t = 0; t < 4; t++){
    int4 mm = ((const int4*)mp)[t];
    if (mm.x == 1) f[4*t]   = -1e9f;
    if (mm.y == 1) f[4*t+1] = -1e9f;
    if (mm.z == 1) f[4*t+2] = -1e9f;
    if (mm.w == 1) f[4*t+3] = -1e9f;
  }
  float m = f[0];
  #pragma unroll
  for (int t = 1; t < 16; t++) m = fmaxf(m, f[t]);
  #pragma unroll
  for (int o = 32; o; o >>= 1) m = fmaxf(m, __shfl_xor(m, o));
  float s = 0.f;
  #pragma unroll
  for (int t = 0; t < 16; t++){ f[t] = __expf(f[t] - m); s += f[t]; }
  #pragma unroll
  for (int o = 32; o; o >>= 1) s += __shfl_xor(s, o);
  float inv = 1.0f / s;
  unsigned int ob[8];
  #pragma unroll
  for (int t = 0; t < 8; t++)
    ob[t] = (unsigned)f2bf(f[2*t] * inv) | ((unsigned)f2bf(f[2*t+1] * inv) << 16);
  *(uint4*)p       = make_uint4(ob[0], ob[1], ob[2], ob[3]);
  *(uint4*)(p + 8) = make_uint4(ob[4], ob[5], ob[6], ob[7]);
}

extern "C" void kernel_launch(void* const* d_in, const int* in_sizes, int n_in,
                              void* d_out, int out_size, void* d_ws, size_t ws_size,
                              hipStream_t stream){
  (void)in_sizes; (void)n_in; (void)out_size; (void)ws_size;
  const float* query = (const float*)d_in[0];
  const float* key_  = (const float*)d_in[1];
  const float* value = (const float*)d_in[2];
  const float* rele  = (const float*)d_in[3];
  const int*   rel   = (const int*)d_in[4];
  const int*   mask  = (const int*)d_in[5];
  const float* Wq = (const float*)d_in[6];  const float* bq = (const float*)d_in[7];
  const float* Wk = (const float*)d_in[8];  const float* bk = (const float*)d_in[9];
  const float* Wv = (const float*)d_in[10]; const float* bv = (const float*)d_in[11];
  const float* Wo = (const float*)d_in[12]; const float* bo = (const float*)d_in[13];
  const float* Wlq = (const float*)d_in[14]; const float* blq = (const float*)d_in[15];
  const float* Wlk = (const float*)d_in[16]; const float* blk = (const float*)d_in[17];
  const float* Wtq = (const float*)d_in[18]; const float* btq = (const float*)d_in[19];
  const float* Wtk = (const float*)d_in[20]; const float* btk = (const float*)d_in[21];

  char* ws = (char*)d_ws;
  auto U = [&](size_t off){ return (unsigned short*)(ws + off); };
  // region 0..64MB: score S; convert staging (dead before score) aliases into it
  unsigned short* S    = U(0);
  unsigned short* qf   = U(0);
  unsigned short* kf   = U(8388608);
  unsigned short* vf   = U(16777216);
  unsigned short* lt   = U(25165824);       // rel_emb bf16: l then t
  unsigned short* WqT  = U(27262976);
  unsigned short* WkT  = U(29360128);
  unsigned short* WvT  = U(31457280);
  unsigned short* WlqT = U(33554432);
  unsigned short* WlkT = U(34603008);
  unsigned short* WtqT = U(35651584);
  unsigned short* WtkT = U(36700160);
  unsigned short* WoT  = U(67108864);
  unsigned short* qs   = U(69206016);       // scaled q  [B,H,N,DK]
  unsigned short* kk   = U(77594624);       // k         [B,H,N,DK]
  unsigned short* vv   = U(85983232);       // v         [B,H,N,DK]
  unsigned short* oh   = U(85983232);       // out_heads aliases vv (vv dead after vtrans)
  unsigned short* vT   = U(94371840);       // v^T       [B,H,DK,N]
  unsigned short* lqs  = U(102760448);      // scaled lq [H,L,DK]
  unsigned short* lks  = U(103809024);      // lk        [H,L,DK]
  unsigned short* Pt   = U(104857600);      // p2c table [B,H,N(j),L(r)]
  unsigned short* Cc   = U(138412032);      // c2p table [B,H,N(i),L(l)]

  const float invs = 1.0f / sqrtf(384.0f);  // 1/sqrt(3*DK)
  dim3 b256(256), b644(64, 4);

  k_convert<<<2048, b256, 0, stream>>>(query, qf, 1048576);
  k_convert<<<2048, b256, 0, stream>>>(key_,  kf, 1048576);
  k_convert<<<2048, b256, 0, stream>>>(value, vf, 1048576);
  k_convert<<<1024, b256, 0, stream>>>(rele,  lt, 262144);

  k_wtrans<<<dim3(16,16), b644, 0, stream>>>(Wq,  WqT,  1024, 1024);
  k_wtrans<<<dim3(16,16), b644, 0, stream>>>(Wk,  WkT,  1024, 1024);
  k_wtrans<<<dim3(16,16), b644, 0, stream>>>(Wv,  WvT,  1024, 1024);
  k_wtrans<<<dim3(16,16), b644, 0, stream>>>(Wo,  WoT,  1024, 1024);
  k_wtrans<<<dim3(8,16),  b644, 0, stream>>>(Wlq, WlqT, 1024, 512);
  k_wtrans<<<dim3(8,16),  b644, 0, stream>>>(Wlk, WlkT, 1024, 512);
  k_wtrans<<<dim3(8,16),  b644, 0, stream>>>(Wtq, WtqT, 1024, 512);
  k_wtrans<<<dim3(8,16),  b644, 0, stream>>>(Wtk, WtkT, 1024, 512);

  // projections (scale folded into q; covers /sqrt(384) of c2c and c2p)
  k_gemm<1><<<dim3(8,32,1), b256, 0, stream>>>(qf,0, WqT,0,0, qs, bq, invs, 4096,1024,1024, 10,0);
  k_gemm<1><<<dim3(8,32,1), b256, 0, stream>>>(kf,0, WkT,0,0, kk, bk, 1.0f, 4096,1024,1024, 10,0);
  k_gemm<1><<<dim3(8,32,1), b256, 0, stream>>>(vf,0, WvT,0,0, vv, bv, 1.0f, 4096,1024,1024, 10,0);
  // rel projections (scale folded into lq; covers /sqrt(384) of p2c)
  k_gemm<1><<<dim3(4,4,1), b256, 0, stream>>>(lt,0,        WlqT,0,0, lqs, blq, invs, 512,512,1024, 9,0);
  k_gemm<1><<<dim3(4,4,1), b256, 0, stream>>>(lt+524288,0, WtqT,0,0, lqs, btq, invs, 512,512,1024, 9,4);
  k_gemm<1><<<dim3(4,4,1), b256, 0, stream>>>(lt,0,        WlkT,0,0, lks, blk, 1.0f, 512,512,1024, 9,0);
  k_gemm<1><<<dim3(4,4,1), b256, 0, stream>>>(lt+524288,0, WtkT,0,0, lks, btk, 1.0f, 512,512,1024, 9,4);

  k_vtrans<<<dim3(2,16,32), b644, 0, stream>>>(vv, vT);

  // tables: Pt[z][j][r] = k_j . lq_r ; Cc[z][i][l] = q_i . lk_l
  k_gemm<0><<<dim3(4,8,32), b256, 0, stream>>>(kk,131072, lqs,65536,7, Pt, nullptr,1.0f, 1024,512,128, 0,0);
  k_gemm<0><<<dim3(4,8,32), b256, 0, stream>>>(qs,131072, lks,65536,7, Cc, nullptr,1.0f, 1024,512,128, 0,0);

  // score = c2c (pure GEMM)
  k_gemm<0><<<dim3(8,8,32), b256, 0, stream>>>(qs,131072, kk,131072,-1, S, nullptr,1.0f, 1024,1024,128, 0,0);

  // S += p2c (LDS-staged Pt rows, in-place RMW)
  k_p2ct<<<dim3(32,32), b256, 0, stream>>>(S, Pt, rel);

  // softmax fused with c2p gather + mask
  k_softmax<<<8192, b256, 0, stream>>>(S, Cc, rel, mask);

  // out_heads = att @ v
  k_gemm<4><<<dim3(1,8,32), b256, 0, stream>>>(S,1048576, vT,131072,-1, oh, nullptr,1.0f, 1024,128,1024, 0,0);

  // final: d_out = out_heads @ Wo + bo   (f32 out)
  k_gemm<2><<<dim3(8,32,1), b256, 0, stream>>>(oh,0, WoT,0,0, d_out, bo, 1.0f, 4096,1024,1024, 0,0);
}

// Round 3
// 500.543 us; speedup vs baseline: 1.2552x; 1.2214x over previous
//
#include <hip/hip_runtime.h>
#include <hip/hip_bf16.h>
#include <stdint.h>
#include <math.h>

// B=4, N=1024, D=1024, H=8, DK=128, L=512. All internal tensors bf16 in ws.
// GEMM convention everywhere: C[m,n] = sum_k A[m,k]*B[n,k]  (B stored [N,K]).

typedef __attribute__((ext_vector_type(8))) __bf16 bf16x8;
typedef __attribute__((ext_vector_type(4))) float f32x4;

#define DEV static __device__ __forceinline__

DEV float bf2f(unsigned short u){ union { unsigned int i; float f; } x; x.i = ((unsigned int)u) << 16; return x.f; }
DEV unsigned short f2bf(float f){ union { float f; unsigned int i; } x; x.f = f;
  unsigned int r = x.i + 0x7FFFu + ((x.i >> 16) & 1u); return (unsigned short)(r >> 16); }

#define GLDS16(gp, lp) __builtin_amdgcn_global_load_lds( \
    (const __attribute__((address_space(1))) void*)(gp), \
    (__attribute__((address_space(3))) void*)(lp), 16, 0, 0)

// ---------------- f32 -> bf16 convert (float4 vectorized) ----------------
__global__ __launch_bounds__(256) void k_convert(const float* __restrict__ src,
                                                 unsigned short* __restrict__ dst, int n4){
  for (int i = blockIdx.x * blockDim.x + threadIdx.x; i < n4; i += gridDim.x * blockDim.x){
    float4 v = ((const float4*)src)[i];
    ushort4 o; o.x = f2bf(v.x); o.y = f2bf(v.y); o.z = f2bf(v.z); o.w = f2bf(v.w);
    ((ushort4*)dst)[i] = o;
  }
}

// ---------------- W [K,N] f32 -> WT [N,K] bf16 (LDS tile transpose) ----------------
__global__ __launch_bounds__(256) void k_wtrans(const float* __restrict__ W,
                                                unsigned short* __restrict__ WT, int K, int N){
  __shared__ unsigned short t[64][65];
  int n0 = blockIdx.x * 64, k0 = blockIdx.y * 64;
  int tx = threadIdx.x, ty = threadIdx.y;
  for (int r = ty; r < 64; r += 4) t[r][tx] = f2bf(W[(long)(k0 + r) * N + n0 + tx]);
  __syncthreads();
  for (int r = ty; r < 64; r += 4) WT[(long)(n0 + r) * K + k0 + tx] = t[tx][r];
}

// ---------------- v [z][1024][128] -> vT [z][128][1024] (bf16) ----------------
__global__ __launch_bounds__(256) void k_vtrans(const unsigned short* __restrict__ V,
                                                unsigned short* __restrict__ VT){
  __shared__ unsigned short t[64][65];
  int z = blockIdx.z, d0 = blockIdx.x * 64, j0 = blockIdx.y * 64;
  int tx = threadIdx.x, ty = threadIdx.y;
  const unsigned short* v = V + (long)z * 131072;
  unsigned short* vt = VT + (long)z * 131072;
  for (int r = ty; r < 64; r += 4) t[r][tx] = v[(j0 + r) * 128 + d0 + tx];
  __syncthreads();
  for (int r = ty; r < 64; r += 4) vt[(d0 + r) * 1024 + j0 + tx] = t[tx][r];
}

// ---------------- GEMM: 128x128 tile, BK=32, 4 waves (2x2), m97 structure ----------------
// MODE 0: plain bf16 out [z][M][N]                       (tables, score c2c)
// MODE 1: bf16 out, (acc+bias)*scale, head-split remap   (projections)
// MODE 2: f32 out [M][N], +bias                          (final projection)
// MODE 4: bf16 out, PV remap -> out_heads[b][i][h*128+dk]
template<int MODE>
__global__ __launch_bounds__(256) void k_gemm(
    const unsigned short* __restrict__ A, long sAz,
    const unsigned short* __restrict__ B, long sBz, int bzMask,
    void* __restrict__ Cout, const float* __restrict__ bias, float scale,
    int M, int N, int K, int logSeq, int headBase)
{
  __shared__ unsigned short Al[128 * 32];
  __shared__ unsigned short Bl[128 * 32];
  const int tid = threadIdx.x;
  const int lane = tid & 63, wave = tid >> 6;
  const int z = blockIdx.z;
  const unsigned short* Az = A + (long)z * sAz;
  const unsigned short* Bz = B + (long)(z & bzMask) * sBz;
  const int m0 = blockIdx.y * 128, n0 = blockIdx.x * 128;
  const int lr = lane & 15, lk = lane >> 4;
  const int wr = wave >> 1, wc = wave & 1;

  f32x4 acc[4][4] = {};

  // staging: thread t loads 16B of row (t>>2), quarter (t&3); LDS is linear row-major [row][32]
  const unsigned short* ga = Az + (long)(m0 + (tid >> 2)) * K + (tid & 3) * 8;
  const unsigned short* gb = Bz + (long)(n0 + (tid >> 2)) * K + (tid & 3) * 8;
  unsigned short* lA = Al + wave * 512;   // wave-uniform LDS base (HW adds lane*16B)
  unsigned short* lB = Bl + wave * 512;
  const long rowStep = (long)64 * K;

  for (int kt = 0; kt < K; kt += 32){
    GLDS16(ga + kt,           lA);
    GLDS16(ga + kt + rowStep, lA + 64 * 32);
    GLDS16(gb + kt,           lB);
    GLDS16(gb + kt + rowStep, lB + 64 * 32);
    __syncthreads();
    bf16x8 af[4], bfr[4];
    #pragma unroll
    for (int mi = 0; mi < 4; mi++) af[mi]  = *(const bf16x8*)&Al[(wr * 64 + mi * 16 + lr) * 32 + lk * 8];
    #pragma unroll
    for (int ni = 0; ni < 4; ni++) bfr[ni] = *(const bf16x8*)&Bl[(wc * 64 + ni * 16 + lr) * 32 + lk * 8];
    #pragma unroll
    for (int mi = 0; mi < 4; mi++)
      #pragma unroll
      for (int ni = 0; ni < 4; ni++)
        acc[mi][ni] = __builtin_amdgcn_mfma_f32_16x16x32_bf16(af[mi], bfr[ni], acc[mi][ni], 0, 0, 0);
    __syncthreads();
  }

  const int seqMask = (1 << logSeq) - 1;
  #pragma unroll
  for (int mi = 0; mi < 4; mi++){
    #pragma unroll
    for (int ni = 0; ni < 4; ni++){
      #pragma unroll
      for (int r = 0; r < 4; r++){
        const int row = m0 + wr * 64 + mi * 16 + (lane >> 4) * 4 + r;  // verified C layout
        const int col = n0 + wc * 64 + ni * 16 + (lane & 15);
        float v = acc[mi][ni][r];
        if constexpr (MODE == 0){
          ((unsigned short*)Cout)[(long)z * M * N + (long)row * N + col] = f2bf(v);
        } else if constexpr (MODE == 1){
          v = (v + bias[col]) * scale;
          long idx = (((long)(row >> logSeq) * 8 + headBase + (col >> 7)) * (long)(seqMask + 1)
                      + (row & seqMask)) * 128 + (col & 127);
          ((unsigned short*)Cout)[idx] = f2bf(v);
        } else if constexpr (MODE == 2){
          ((float*)Cout)[(long)row * N + col] = v + bias[col];
        } else { // MODE 4: out_heads[b][i][h*128+dk]
          ((unsigned short*)Cout)[((long)(z >> 3) * 1024 + row) * 1024 + (z & 7) * 128 + col] = f2bf(v);
        }
      }
    }
  }
}

// ---------------- p2c: S[z][i][j] += Pt[z][j][ rel[z][j][i] ]  (coalesced, LDS transpose) ----
// Block = (z, 32 j-rows). Pt rows staged in LDS once. Per 64-i strip:
//   gather phase: wave w handles j rows w*8..w*8+7, rel read lane-contiguous in i (coalesced),
//                 gathered values -> padded LDS tile T[32 j][66] (conflict-free column reads).
//   add phase: thread t owns (i = i0 + t>>2, j-quarter = t&3); S read/add/write as uint4,
//              4 threads per row -> contiguous 64B lines. All global traffic coalesced.
__global__ __launch_bounds__(256) void k_p2cadd(unsigned short* __restrict__ S,
    const unsigned short* __restrict__ Pt, const int* __restrict__ rel){
  __shared__ unsigned short Ptl[32][512];   // 32 KB
  __shared__ unsigned short T[32][66];      // padded: bank = il/2 + (jq+jj)*33 mod 32
  const int tid = threadIdx.x, l = tid & 63, w = tid >> 6;
  const int z = blockIdx.y, j0 = blockIdx.x * 32;
  const long zb = (long)z << 20;
  {
    const char* g = (const char*)Pt + ((long)z * 1024 + j0) * 1024;  // 32 rows x 1KB
    char* lb = (char*)&Ptl[0][0];
    #pragma unroll
    for (int it = 0; it < 8; it++)
      GLDS16(g + it * 4096 + w * 1024 + l * 16, lb + it * 4096 + w * 1024);
  }
  const int jb = w * 8;               // gather-phase j-rows for this wave
  const int il = tid >> 2;            // add-phase i (0..63)
  const int jq = (tid & 3) * 8;       // add-phase j-quarter
  const int* rbase = rel + zb + (long)(j0 + jb) * 1024 + l;
  for (int i0 = 0; i0 < 1024; i0 += 64){
    __syncthreads();  // iter 0: Pt staging drained; later: protect T from prev readers
    unsigned short vals[8];
    #pragma unroll
    for (int jj = 0; jj < 8; jj++){
      int rv = rbase[jj * 1024 + i0];
      vals[jj] = Ptl[jb + jj][rv & 511];
    }
    #pragma unroll
    for (int jj = 0; jj < 8; jj++) T[jb + jj][l] = vals[jj];
    __syncthreads();
    unsigned short* sp = S + zb + (long)(i0 + il) * 1024 + j0 + jq;
    uint4 a = *(const uint4*)sp;
    unsigned int aw[4] = {a.x, a.y, a.z, a.w};
    float f[8];
    #pragma unroll
    for (int e = 0; e < 4; e++){
      f[2*e]   = bf2f((unsigned short)(aw[e] & 0xFFFFu));
      f[2*e+1] = bf2f((unsigned short)(aw[e] >> 16));
    }
    #pragma unroll
    for (int jj = 0; jj < 8; jj++) f[jj] += bf2f(T[jq + jj][il]);
    #pragma unroll
    for (int e = 0; e < 4; e++)
      aw[e] = (unsigned)f2bf(f[2*e]) | ((unsigned)f2bf(f[2*e+1]) << 16);
    *(uint4*)sp = make_uint4(aw[0], aw[1], aw[2], aw[3]);
  }
}

// ---------------- softmax fused with c2p gather + mask, in-place, 1 wave/row ----------------
__global__ __launch_bounds__(256) void k_softmax(unsigned short* __restrict__ S,
    const unsigned short* __restrict__ Cc, const int* __restrict__ rel,
    const int* __restrict__ maskp){
  __shared__ unsigned short crow[4][512];
  const int w = threadIdx.x >> 6, lane = threadIdx.x & 63;
  const long row = (long)blockIdx.x * 4 + w;
  const int z = (int)(row >> 10), i = (int)(row & 1023);
  *(uint4*)&crow[w][lane * 8] = *(const uint4*)&Cc[row * 512 + lane * 8];
  __syncthreads();
  unsigned short* p = S + row * 1024 + lane * 16;
  const int* rp = rel + row * 1024 + lane * 16;
  const int* mp = maskp + ((((long)(z >> 3)) << 10) + i) * 1024 + lane * 16;
  uint4 w0 = *(const uint4*)p;
  uint4 w1 = *(const uint4*)(p + 8);
  unsigned int wa[8] = {w0.x, w0.y, w0.z, w0.w, w1.x, w1.y, w1.z, w1.w};
  float f[16];
  #pragma unroll
  for (int t = 0; t < 8; t++){
    f[2*t]   = bf2f((unsigned short)(wa[t] & 0xFFFFu));
    f[2*t+1] = bf2f((unsigned short)(wa[t] >> 16));
  }
  #pragma unroll
  for (int t = 0; t < 4; t++){
    int4 rr = ((const int4*)rp)[t];
    f[4*t]   += bf2f(crow[w][rr.x & 511]);
    f[4*t+1] += bf2f(crow[w][rr.y & 511]);
    f[4*t+2] += bf2f(crow[w][rr.z & 511]);
    f[4*t+3] += bf2f(crow[w][rr.w & 511]);
  }
  #pragma unroll
  for (int t = 0; t < 4; t++){
    int4 mm = ((const int4*)mp)[t];
    if (mm.x == 1) f[4*t]   = -1e9f;
    if (mm.y == 1) f[4*t+1] = -1e9f;
    if (mm.z == 1) f[4*t+2] = -1e9f;
    if (mm.w == 1) f[4*t+3] = -1e9f;
  }
  float m = f[0];
  #pragma unroll
  for (int t = 1; t < 16; t++) m = fmaxf(m, f[t]);
  #pragma unroll
  for (int o = 32; o; o >>= 1) m = fmaxf(m, __shfl_xor(m, o));
  float s = 0.f;
  #pragma unroll
  for (int t = 0; t < 16; t++){ f[t] = __expf(f[t] - m); s += f[t]; }
  #pragma unroll
  for (int o = 32; o; o >>= 1) s += __shfl_xor(s, o);
  float inv = 1.0f / s;
  unsigned int ob[8];
  #pragma unroll
  for (int t = 0; t < 8; t++)
    ob[t] = (unsigned)f2bf(f[2*t] * inv) | ((unsigned)f2bf(f[2*t+1] * inv) << 16);
  *(uint4*)p       = make_uint4(ob[0], ob[1], ob[2], ob[3]);
  *(uint4*)(p + 8) = make_uint4(ob[4], ob[5], ob[6], ob[7]);
}

extern "C" void kernel_launch(void* const* d_in, const int* in_sizes, int n_in,
                              void* d_out, int out_size, void* d_ws, size_t ws_size,
                              hipStream_t stream){
  (void)in_sizes; (void)n_in; (void)out_size; (void)ws_size;
  const float* query = (const float*)d_in[0];
  const float* key_  = (const float*)d_in[1];
  const float* value = (const float*)d_in[2];
  const float* rele  = (const float*)d_in[3];
  const int*   rel   = (const int*)d_in[4];
  const int*   mask  = (const int*)d_in[5];
  const float* Wq = (const float*)d_in[6];  const float* bq = (const float*)d_in[7];
  const float* Wk = (const float*)d_in[8];  const float* bk = (const float*)d_in[9];
  const float* Wv = (const float*)d_in[10]; const float* bv = (const float*)d_in[11];
  const float* Wo = (const float*)d_in[12]; const float* bo = (const float*)d_in[13];
  const float* Wlq = (const float*)d_in[14]; const float* blq = (const float*)d_in[15];
  const float* Wlk = (const float*)d_in[16]; const float* blk = (const float*)d_in[17];
  const float* Wtq = (const float*)d_in[18]; const float* btq = (const float*)d_in[19];
  const float* Wtk = (const float*)d_in[20]; const float* btk = (const float*)d_in[21];

  char* ws = (char*)d_ws;
  auto U = [&](size_t off){ return (unsigned short*)(ws + off); };
  // region 0..64MB: score S; convert staging (dead before score) aliases into it
  unsigned short* S    = U(0);
  unsigned short* qf   = U(0);
  unsigned short* kf   = U(8388608);
  unsigned short* vf   = U(16777216);
  unsigned short* lt   = U(25165824);       // rel_emb bf16: l then t
  unsigned short* WqT  = U(27262976);
  unsigned short* WkT  = U(29360128);
  unsigned short* WvT  = U(31457280);
  unsigned short* WlqT = U(33554432);
  unsigned short* WlkT = U(34603008);
  unsigned short* WtqT = U(35651584);
  unsigned short* WtkT = U(36700160);
  unsigned short* WoT  = U(67108864);
  unsigned short* qs   = U(69206016);       // scaled q  [B,H,N,DK]
  unsigned short* kk   = U(77594624);       // k         [B,H,N,DK]
  unsigned short* vv   = U(85983232);       // v         [B,H,N,DK]
  unsigned short* oh   = U(85983232);       // out_heads aliases vv (vv dead after vtrans)
  unsigned short* vT   = U(94371840);       // v^T       [B,H,DK,N]
  unsigned short* lqs  = U(102760448);      // scaled lq [H,L,DK]
  unsigned short* lks  = U(103809024);      // lk        [H,L,DK]
  unsigned short* Pt   = U(104857600);      // p2c table [B,H,N(j),L(r)]
  unsigned short* Cc   = U(138412032);      // c2p table [B,H,N(i),L(l)]

  const float invs = 1.0f / sqrtf(384.0f);  // 1/sqrt(3*DK)
  dim3 b256(256), b644(64, 4);

  k_convert<<<2048, b256, 0, stream>>>(query, qf, 1048576);
  k_convert<<<2048, b256, 0, stream>>>(key_,  kf, 1048576);
  k_convert<<<2048, b256, 0, stream>>>(value, vf, 1048576);
  k_convert<<<1024, b256, 0, stream>>>(rele,  lt, 262144);

  k_wtrans<<<dim3(16,16), b644, 0, stream>>>(Wq,  WqT,  1024, 1024);
  k_wtrans<<<dim3(16,16), b644, 0, stream>>>(Wk,  WkT,  1024, 1024);
  k_wtrans<<<dim3(16,16), b644, 0, stream>>>(Wv,  WvT,  1024, 1024);
  k_wtrans<<<dim3(16,16), b644, 0, stream>>>(Wo,  WoT,  1024, 1024);
  k_wtrans<<<dim3(8,16),  b644, 0, stream>>>(Wlq, WlqT, 1024, 512);
  k_wtrans<<<dim3(8,16),  b644, 0, stream>>>(Wlk, WlkT, 1024, 512);
  k_wtrans<<<dim3(8,16),  b644, 0, stream>>>(Wtq, WtqT, 1024, 512);
  k_wtrans<<<dim3(8,16),  b644, 0, stream>>>(Wtk, WtkT, 1024, 512);

  // projections (scale folded into q; covers /sqrt(384) of c2c and c2p)
  k_gemm<1><<<dim3(8,32,1), b256, 0, stream>>>(qf,0, WqT,0,0, qs, bq, invs, 4096,1024,1024, 10,0);
  k_gemm<1><<<dim3(8,32,1), b256, 0, stream>>>(kf,0, WkT,0,0, kk, bk, 1.0f, 4096,1024,1024, 10,0);
  k_gemm<1><<<dim3(8,32,1), b256, 0, stream>>>(vf,0, WvT,0,0, vv, bv, 1.0f, 4096,1024,1024, 10,0);
  // rel projections (scale folded into lq; covers /sqrt(384) of p2c)
  k_gemm<1><<<dim3(4,4,1), b256, 0, stream>>>(lt,0,        WlqT,0,0, lqs, blq, invs, 512,512,1024, 9,0);
  k_gemm<1><<<dim3(4,4,1), b256, 0, stream>>>(lt+524288,0, WtqT,0,0, lqs, btq, invs, 512,512,1024, 9,4);
  k_gemm<1><<<dim3(4,4,1), b256, 0, stream>>>(lt,0,        WlkT,0,0, lks, blk, 1.0f, 512,512,1024, 9,0);
  k_gemm<1><<<dim3(4,4,1), b256, 0, stream>>>(lt+524288,0, WtkT,0,0, lks, btk, 1.0f, 512,512,1024, 9,4);

  k_vtrans<<<dim3(2,16,32), b644, 0, stream>>>(vv, vT);

  // tables: Pt[z][j][r] = k_j . lq_r ; Cc[z][i][l] = q_i . lk_l
  k_gemm<0><<<dim3(4,8,32), b256, 0, stream>>>(kk,131072, lqs,65536,7, Pt, nullptr,1.0f, 1024,512,128, 0,0);
  k_gemm<0><<<dim3(4,8,32), b256, 0, stream>>>(qs,131072, lks,65536,7, Cc, nullptr,1.0f, 1024,512,128, 0,0);

  // score = c2c (pure GEMM)
  k_gemm<0><<<dim3(8,8,32), b256, 0, stream>>>(qs,131072, kk,131072,-1, S, nullptr,1.0f, 1024,1024,128, 0,0);

  // S += p2c (coalesced gather + LDS transpose + RMW)
  k_p2cadd<<<dim3(32,32), b256, 0, stream>>>(S, Pt, rel);

  // softmax fused with c2p gather + mask
  k_softmax<<<8192, b256, 0, stream>>>(S, Cc, rel, mask);

  // out_heads = att @ v
  k_gemm<4><<<dim3(1,8,32), b256, 0, stream>>>(S,1048576, vT,131072,-1, oh, nullptr,1.0f, 1024,128,1024, 0,0);

  // final: d_out = out_heads @ Wo + bo   (f32 out)
  k_gemm<2><<<dim3(8,32,1), b256, 0, stream>>>(oh,0, WoT,0,0, d_out, bo, 1.0f, 4096,1024,1024, 0,0);
}